// Round 5
// baseline (351.185 us; speedup 1.0000x reference)
//
#include <hip/hip_runtime.h>
#include <cstddef>

// Problem constants (from reference)
constexpr int kC = 81;            // NUM_CLASSES + 1
constexpr int kNumBase = 60;      // NUM_CLASSES // 4 * 3
constexpr int kNumClasses = 80;
constexpr float kWNovel = 1.0f / 10.0f;   // 1/SHOT
constexpr float kWBase = kWNovel / 3.0f;
constexpr float kWNeg = 0.001f;
constexpr float kEpsDiff = 1e-3f;
constexpr float kMaxLog = 5.0f;
constexpr float kMaxLoss = 1.0f;
constexpr int kMinSamp = 2;
constexpr int kShadows = 8;       // global-accumulator striping factor

// 16-byte vector with 4-byte alignment: lets the compiler issue wide global
// loads from float-aligned addresses (gfx9+ supports unaligned vector loads).
typedef float float4u __attribute__((ext_vector_type(4), aligned(4)));

// R3 structure (direct global loads, no staging, no hot-loop barriers) with
// the finalize FUSED via the last-block-done pattern:
//   - each wave grid-strides over 16-row groups; 4 lanes cooperate per row
//     (21 columns each in VGPRs; quad q=3 covers [60,81) with 3 overlap
//     columns masked out of the sums),
//   - per-class (sum,count) -> LDS histogram -> one of 8 global shadow
//     copies via device-scope atomics,
//   - last block to finish (atomic done-counter) reduces the shadows and
//     writes the 3 outputs. No ordering assumption: whichever block is last
//     finalizes; __threadfence + agent-scope loads handle XCD coherence.
__global__ __launch_bounds__(256) void adl_main(
    const float* __restrict__ cls,
    const int* __restrict__ labels,
    const float* __restrict__ lw,
    float* __restrict__ gsum,
    int* __restrict__ gcnt,
    unsigned* __restrict__ done,
    float* __restrict__ out,
    int n) {
  __shared__ float ssum[kC];
  __shared__ int scnt[kC];
  __shared__ int slast;
  const int tid = threadIdx.x;
  if (tid < kC) { ssum[tid] = 0.0f; scnt[tid] = 0; }
  __syncthreads();  // histogram init; hot loop has no block barriers

  const int lane = tid & 63;
  const int wave = tid >> 6;
  const int q = lane & 3;                  // quad index within row
  const int rsub = lane >> 2;              // row within 16-row group
  const int gw = blockIdx.x * (blockDim.x >> 6) + wave;
  const int nw = gridDim.x * (blockDim.x >> 6);
  const int ngroups = n >> 4;              // N divisible by 16
  const int c0 = (q < 3) ? q * 21 : 60;    // first column for this lane

  for (int g = gw; g < ngroups; g += nw) {
    const int row = (g << 4) + rsub;
    const float* rp = cls + (size_t)row * kC;

    // ---- load 21 columns: 5 x 16B vector loads (align 4) + 1 scalar ----
    float x[21];
    const float* p = rp + c0;
#pragma unroll
    for (int k = 0; k < 5; ++k) {
      float4u v = *(const float4u*)(p + 4 * k);
      x[4 * k + 0] = v.x; x[4 * k + 1] = v.y;
      x[4 * k + 2] = v.z; x[4 * k + 3] = v.w;
    }
    x[20] = p[20];

    // ---- softmax max (duplicated cols harmless for max) ----
    float m = x[0];
#pragma unroll
    for (int j = 1; j < 21; ++j) m = fmaxf(m, x[j]);
    m = fmaxf(m, __shfl_xor(m, 1));
    m = fmaxf(m, __shfl_xor(m, 2));

    // ---- exp + denom (mask the 3 duplicated cols on q==3) ----
    float s = 0.0f;
#pragma unroll
    for (int j = 0; j < 21; ++j) {
      x[j] = __expf(x[j] - m);
      s += (j < 3 && q == 3) ? 0.0f : x[j];
    }
    s += __shfl_xor(s, 1);
    s += __shfl_xor(s, 2);
    const float inv = 1.0f / s;

    const int label = labels[row];         // 4 dup lanes/row, L1-hot
    const float p_true = __expf(rp[label] - m) * inv;  // extra L1-hot load

    const float om = fminf(fmaxf(1.0f - p_true, 1e-4f), 1.0f);
    const float w = om * om;

    // ---- margin terms: min(-log(clip(p_true - p_c, 1e-3, 1)), 5) ----
    float t = 0.0f;
#pragma unroll
    for (int j = 0; j < 21; ++j) {
      const float d = fminf(fmaxf(p_true - x[j] * inv, kEpsDiff), 1.0f);
      const float term = fminf(-__logf(d), kMaxLog);
      t += (j < 3 && q == 3) ? 0.0f : term;
    }
    t += __shfl_xor(t, 1);
    t += __shfl_xor(t, 2);

    // True-column term is exactly 5 (clip(0,1e-3,1)=1e-3, -log(1e-3)=6.9>5),
    // so the sum over the C-1 'other' columns is (t - 5).
    if (q == 0 && lw[row] > 0.0f) {
      atomicAdd(&ssum[label], w * (t - kMaxLog));
      atomicAdd(&scnt[label], 1);
    }
  }

  // ---- flush block histogram to one of 8 shadow copies ----
  __syncthreads();
  const int sh = blockIdx.x & (kShadows - 1);
  if (tid < kC && scnt[tid] != 0) {
    atomicAdd(&gsum[sh * kC + tid], ssum[tid]);
    atomicAdd(&gcnt[sh * kC + tid], scnt[tid]);
  }
  __threadfence();   // release: make flush visible before signaling done
  __syncthreads();   // all threads of this block have flushed+fenced

  if (tid == 0) {
    const unsigned old = atomicAdd(done, 1u);
    slast = (old == gridDim.x - 1) ? 1 : 0;
  }
  __syncthreads();
  if (slast == 0 || tid >= 64) return;

  // ---- last block: finalize (one wave) ----
  __threadfence();   // acquire side
  float sb = 0.0f, sn = 0.0f, sg = 0.0f;
  int nb = 0, nn = 0, ng = 0;
#pragma unroll
  for (int k = 0; k < 2; ++k) {
    const int c = lane + k * 64;
    if (c < kC) {
      float sm = 0.0f;
      int cnt = 0;
#pragma unroll
      for (int s2 = 0; s2 < kShadows; ++s2) {
        sm += __hip_atomic_load(&gsum[s2 * kC + c], __ATOMIC_RELAXED,
                                __HIP_MEMORY_SCOPE_AGENT);
        cnt += __hip_atomic_load(&gcnt[s2 * kC + c], __ATOMIC_RELAXED,
                                 __HIP_MEMORY_SCOPE_AGENT);
      }
      if (c < kNumBase) {
        if (cnt >= kMinSamp) { sb += sm; nb += cnt; }
      } else if (c < kNumClasses) {
        if (cnt >= kMinSamp) { sn += sm; nn += cnt; }
      } else {
        sg += sm; ng += cnt;
      }
    }
  }
#pragma unroll
  for (int off = 32; off > 0; off >>= 1) {
    sb += __shfl_xor(sb, off);
    sn += __shfl_xor(sn, off);
    sg += __shfl_xor(sg, off);
    nb += __shfl_xor(nb, off);
    nn += __shfl_xor(nn, off);
    ng += __shfl_xor(ng, off);
  }
  if (lane == 0) {
    const double denom = (double)(kC - 1);
    double lb = (nb > 0) ? (double)sb / ((double)nb * denom) * (double)kWBase : 0.0;
    double ln = (nn > 0) ? (double)sn / ((double)nn * denom) * (double)kWNovel : 0.0;
    double lg = (ng > 0) ? (double)sg / ((double)ng * denom) * (double)kWNeg : 0.0;
    out[0] = (float)fmin(lb, (double)kMaxLoss);
    out[1] = (float)fmin(ln, (double)kMaxLoss);
    out[2] = (float)fmin(lg, (double)kMaxLoss);
  }
}

extern "C" void kernel_launch(void* const* d_in, const int* in_sizes, int n_in,
                              void* d_out, int out_size, void* d_ws, size_t ws_size,
                              hipStream_t stream) {
  const float* cls = (const float*)d_in[0];
  const int* labels = (const int*)d_in[1];
  const float* lw = (const float*)d_in[2];
  float* out = (float*)d_out;
  const int n = in_sizes[1];  // N, from labels

  float* gsum = (float*)d_ws;                                       // 8*81 floats
  int* gcnt = (int*)((char*)d_ws + kShadows * kC * sizeof(float));  // 8*81 ints
  unsigned* done = (unsigned*)((char*)d_ws +
                               2 * kShadows * kC * sizeof(float));  // 1 counter

  // ws is re-poisoned to 0xAA before every call — zero accumulators + counter.
  hipMemsetAsync(d_ws, 0,
                 2 * kShadows * kC * sizeof(float) + sizeof(unsigned), stream);

  // 2048 blocks x 256 threads = 8192 waves; 16384 16-row groups -> 2/wave.
  // LDS 660 B, ~40 VGPR -> full occupancy; finalize fused via last-block-done.
  adl_main<<<2048, 256, 0, stream>>>(cls, labels, lw, gsum, gcnt, done, out, n);
}

// Round 6
// 128.150 us; speedup vs baseline: 2.7404x; 2.7404x over previous
//
#include <hip/hip_runtime.h>
#include <cstddef>

// Problem constants (from reference)
constexpr int kC = 81;            // NUM_CLASSES + 1
constexpr int kNumBase = 60;      // NUM_CLASSES // 4 * 3
constexpr int kNumClasses = 80;
constexpr float kWNovel = 1.0f / 10.0f;   // 1/SHOT
constexpr float kWBase = kWNovel / 3.0f;
constexpr float kWNeg = 0.001f;
constexpr float kEpsDiff = 1e-3f;
constexpr float kMaxLog = 5.0f;
constexpr float kMaxLoss = 1.0f;
constexpr int kMinSamp = 2;
constexpr int kShadows = 8;       // global-accumulator striping factor

// 16-byte vector with 4-byte alignment: lets us issue wide global loads
// from addresses that are only float-aligned.
typedef float float4u __attribute__((ext_vector_type(4), aligned(4)));

// R3 configuration (best measured: 128.8 us total). Two kernels — fusing the
// finalize into adl_main (R5) collapsed register allocation (VGPR 40->24,
// x[21] no longer register-resident, 10x slowdown). Keep the hot kernel's
// code footprint minimal so the x[21] array stays in VGPRs.
//
// Each wave grid-strides over 16-row groups; 4 lanes cooperate per row.
// Lane quad q in {0,1,2} loads columns [21q, 21q+21); q=3 loads [60,81)
// (3 overlap columns masked out of the sums). All 21 values live in VGPRs;
// reductions are 2-step intra-quad shuffles. Per-class (sum,count) -> LDS
// histogram -> one of 8 global shadow copies (8x less atomic contention).
__global__ __launch_bounds__(256) void adl_main(
    const float* __restrict__ cls,
    const int* __restrict__ labels,
    const float* __restrict__ lw,
    float* __restrict__ gsum,
    int* __restrict__ gcnt,
    int n) {
  __shared__ float ssum[kC];
  __shared__ int scnt[kC];
  const int tid = threadIdx.x;
  if (tid < kC) { ssum[tid] = 0.0f; scnt[tid] = 0; }
  __syncthreads();

  const int lane = tid & 63;
  const int wave = tid >> 6;
  const int q = lane & 3;                  // quad index within row
  const int rsub = lane >> 2;              // row within 16-row group
  const int gw = blockIdx.x * (blockDim.x >> 6) + wave;
  const int nw = gridDim.x * (blockDim.x >> 6);
  const int ngroups = n >> 4;              // N divisible by 16
  const int c0 = (q < 3) ? q * 21 : 60;    // first column for this lane

  for (int g = gw; g < ngroups; g += nw) {
    const int row = (g << 4) + rsub;
    const float* rp = cls + (size_t)row * kC;

    // ---- load 21 columns: 5 x 16B vector loads (align 4) + 1 scalar ----
    float x[21];
    const float* p = rp + c0;
#pragma unroll
    for (int k = 0; k < 5; ++k) {
      float4u v = *(const float4u*)(p + 4 * k);
      x[4 * k + 0] = v.x; x[4 * k + 1] = v.y;
      x[4 * k + 2] = v.z; x[4 * k + 3] = v.w;
    }
    x[20] = p[20];

    // ---- softmax max (duplicated cols harmless for max) ----
    float m = x[0];
#pragma unroll
    for (int j = 1; j < 21; ++j) m = fmaxf(m, x[j]);
    m = fmaxf(m, __shfl_xor(m, 1));
    m = fmaxf(m, __shfl_xor(m, 2));

    // ---- exp + denom (mask the 3 duplicated cols on q==3) ----
    float s = 0.0f;
#pragma unroll
    for (int j = 0; j < 21; ++j) {
      x[j] = __expf(x[j] - m);
      s += (j < 3 && q == 3) ? 0.0f : x[j];
    }
    s += __shfl_xor(s, 1);
    s += __shfl_xor(s, 2);
    const float inv = 1.0f / s;

    const int label = labels[row];         // 4 dup lanes/row, L1-hot
    const float p_true = __expf(rp[label] - m) * inv;  // extra L1-hot load

    const float om = fminf(fmaxf(1.0f - p_true, 1e-4f), 1.0f);
    const float w = om * om;

    // ---- margin terms: min(-log(clip(p_true - p_c, 1e-3, 1)), 5) ----
    float t = 0.0f;
#pragma unroll
    for (int j = 0; j < 21; ++j) {
      const float d = fminf(fmaxf(p_true - x[j] * inv, kEpsDiff), 1.0f);
      const float term = fminf(-__logf(d), kMaxLog);
      t += (j < 3 && q == 3) ? 0.0f : term;
    }
    t += __shfl_xor(t, 1);
    t += __shfl_xor(t, 2);

    // True-column term is exactly 5 (clip(0,1e-3,1)=1e-3, -log(1e-3)=6.9>5),
    // so the sum over the C-1 'other' columns is (t - 5).
    if (q == 0) {
      if (lw[row] > 0.0f) {
        atomicAdd(&ssum[label], w * (t - kMaxLog));
        atomicAdd(&scnt[label], 1);
      }
    }
  }

  __syncthreads();
  const int sh = blockIdx.x & (kShadows - 1);
  if (tid < kC && scnt[tid] != 0) {
    atomicAdd(&gsum[sh * kC + tid], ssum[tid]);
    atomicAdd(&gcnt[sh * kC + tid], scnt[tid]);
  }
}

// One wave: lane handles classes lane and lane+64 across the 8 shadow copies.
__global__ __launch_bounds__(64) void adl_final(const float* __restrict__ gsum,
                                                const int* __restrict__ gcnt,
                                                float* __restrict__ out) {
  const int lane = threadIdx.x;
  float sb = 0.0f, sn = 0.0f, sg = 0.0f;
  int nb = 0, nn = 0, ng = 0;
#pragma unroll
  for (int k = 0; k < 2; ++k) {
    const int c = lane + k * 64;
    if (c < kC) {
      float sm = 0.0f;
      int cnt = 0;
#pragma unroll
      for (int sh = 0; sh < kShadows; ++sh) {
        sm += gsum[sh * kC + c];
        cnt += gcnt[sh * kC + c];
      }
      if (c < kNumBase) {
        if (cnt >= kMinSamp) { sb += sm; nb += cnt; }
      } else if (c < kNumClasses) {
        if (cnt >= kMinSamp) { sn += sm; nn += cnt; }
      } else {
        sg += sm; ng += cnt;
      }
    }
  }
#pragma unroll
  for (int off = 32; off > 0; off >>= 1) {
    sb += __shfl_xor(sb, off);
    sn += __shfl_xor(sn, off);
    sg += __shfl_xor(sg, off);
    nb += __shfl_xor(nb, off);
    nn += __shfl_xor(nn, off);
    ng += __shfl_xor(ng, off);
  }
  if (lane == 0) {
    const double denom = (double)(kC - 1);
    double lb = (nb > 0) ? (double)sb / ((double)nb * denom) * (double)kWBase : 0.0;
    double ln = (nn > 0) ? (double)sn / ((double)nn * denom) * (double)kWNovel : 0.0;
    double lg = (ng > 0) ? (double)sg / ((double)ng * denom) * (double)kWNeg : 0.0;
    out[0] = (float)fmin(lb, (double)kMaxLoss);
    out[1] = (float)fmin(ln, (double)kMaxLoss);
    out[2] = (float)fmin(lg, (double)kMaxLoss);
  }
}

extern "C" void kernel_launch(void* const* d_in, const int* in_sizes, int n_in,
                              void* d_out, int out_size, void* d_ws, size_t ws_size,
                              hipStream_t stream) {
  const float* cls = (const float*)d_in[0];
  const int* labels = (const int*)d_in[1];
  const float* lw = (const float*)d_in[2];
  float* out = (float*)d_out;
  const int n = in_sizes[1];  // N, from labels

  float* gsum = (float*)d_ws;                                       // 8*81 floats
  int* gcnt = (int*)((char*)d_ws + kShadows * kC * sizeof(float));  // 8*81 ints

  // ws is re-poisoned to 0xAA before every call — zero our accumulators.
  hipMemsetAsync(d_ws, 0, kShadows * kC * (sizeof(float) + sizeof(int)), stream);

  // 2048 blocks x 256 threads = 8192 waves; 16384 16-row groups -> 2/wave.
  // LDS 648 B, ~40 VGPR -> full 32 waves/CU occupancy, no hot-loop barriers.
  adl_main<<<2048, 256, 0, stream>>>(cls, labels, lw, gsum, gcnt, n);
  adl_final<<<1, 64, 0, stream>>>(gsum, gcnt, out);
}